// Round 3
// baseline (312.532 us; speedup 1.0000x reference)
//
#include <hip/hip_runtime.h>

// CrossNet fused kernel: out = initial * (X @ alphas) + X + bias
// B=16384 rows, D=2048 cols, fp32.
//
// R3: persistent waves + software pipeline. R0/R2 showed duration is
// invariant to occupancy (72% vs 36% -> same 111us), so the limiter is
// not in-flight load count: the one-row-per-wave schedule gives every
// wave the same read-burst / reduce-bubble / write-burst phases, and
// the launch-synchronized waves present the HBM controller with
// alternating read/write epochs (~1.2 TB/s per stream, symmetric).
// Here 4096 persistent waves each process 4 rows: per iteration we
// issue I[r] and X[r+1], then dot+reduce X[r] which arrived a full
// iteration ago (zero wait), then store. Waves desynchronize across
// iterations -> continuously mixed r/w streams; the reduce bubble is
// filled with the next row's loads. Alphas+bias live in LDS (staged
// once per block) so the per-row dot does no VMEM.

#define CN_D 2048
#define CN_ROWS 16384
#define CN_BLOCKS 1024           // 4096 waves total
#define CN_WAVES (CN_BLOCKS * 4)
#define CN_ROWS_PER_WAVE (CN_ROWS / CN_WAVES)   // = 4

typedef float vfloat4 __attribute__((ext_vector_type(4)));

__global__ __launch_bounds__(256, 4) void crossnet_kernel(
    const float* __restrict__ initial,
    const float* __restrict__ X,
    const float* __restrict__ alphas,
    const float* __restrict__ bias,
    float* __restrict__ out)
{
    __shared__ float lds_a[CN_D];
    __shared__ float lds_b[CN_D];

    const int wave = threadIdx.x >> 6;          // 0..3
    const int lane = threadIdx.x & 63;
    const int r0   = (blockIdx.x << 2) + wave;  // first row; stride 4096

    // ---- prologue: issue row r0's X loads before anything else ----
    vfloat4 xc[8];
    {
        const vfloat4* Xr = (const vfloat4*)(X + (size_t)r0 * CN_D);
#pragma unroll
        for (int k = 0; k < 8; ++k) xc[k] = Xr[(k << 6) + lane];
    }

    // ---- stage alphas + bias into LDS, once per block ----
    {
        const vfloat4* A4 = (const vfloat4*)alphas;
        const vfloat4* B4 = (const vfloat4*)bias;
        vfloat4* LA = (vfloat4*)lds_a;
        vfloat4* LB = (vfloat4*)lds_b;
        const int t = threadIdx.x;              // 0..255; D/4 = 512 chunks
        LA[t]       = A4[t];
        LA[t + 256] = A4[t + 256];
        LB[t]       = B4[t];
        LB[t + 256] = B4[t + 256];
    }
    __syncthreads();   // only barrier in the kernel

    const vfloat4* LA = (const vfloat4*)lds_a;
    const vfloat4* LB = (const vfloat4*)lds_b;

#pragma unroll
    for (int it = 0; it < CN_ROWS_PER_WAVE; ++it) {
        const int r = r0 + (it << 12);          // +4096 rows per iter
        const vfloat4* Ir = (const vfloat4*)(initial + (size_t)r * CN_D);
        vfloat4*       Or = (vfloat4*)(out     + (size_t)r * CN_D);

        // Issue this row's initial loads (consumed after the reduce;
        // latency hidden under dot + butterfly).
        vfloat4 fi[8];
#pragma unroll
        for (int k = 0; k < 8; ++k) fi[k] = Ir[(k << 6) + lane];

        // Issue NEXT row's X loads (consumed next iteration; a full
        // iteration of latency slack).
        vfloat4 xn[8];
        if (it + 1 < CN_ROWS_PER_WAVE) {
            const vfloat4* Xn = (const vfloat4*)(X + (size_t)(r + 4096) * CN_D);
#pragma unroll
            for (int k = 0; k < 8; ++k) xn[k] = Xn[(k << 6) + lane];
        }

        // Dot on the resident row against LDS alphas: no VMEM wait.
        float acc = 0.0f;
#pragma unroll
        for (int k = 0; k < 8; ++k) {
            const vfloat4 a = LA[(k << 6) + lane];
            acc = fmaf(xc[k].x, a.x, acc);
            acc = fmaf(xc[k].y, a.y, acc);
            acc = fmaf(xc[k].z, a.z, acc);
            acc = fmaf(xc[k].w, a.w, acc);
        }

        // 64-lane butterfly; xor leaves the full sum in every lane.
#pragma unroll
        for (int off = 32; off > 0; off >>= 1)
            acc += __shfl_xor(acc, off, 64);

        // Epilogue: fi arrived during dot+reduce; bias from LDS.
#pragma unroll
        for (int k = 0; k < 8; ++k) {
            const vfloat4 b = LB[(k << 6) + lane];
            vfloat4 o;
            o.x = fmaf(fi[k].x, acc, xc[k].x + b.x);
            o.y = fmaf(fi[k].y, acc, xc[k].y + b.y);
            o.z = fmaf(fi[k].z, acc, xc[k].z + b.z);
            o.w = fmaf(fi[k].w, acc, xc[k].w + b.w);
            Or[(k << 6) + lane] = o;
        }

        // Rotate the pipeline (renamed away by the full unroll).
        if (it + 1 < CN_ROWS_PER_WAVE) {
#pragma unroll
            for (int k = 0; k < 8; ++k) xc[k] = xn[k];
        }
    }
}

extern "C" void kernel_launch(void* const* d_in, const int* in_sizes, int n_in,
                              void* d_out, int out_size, void* d_ws, size_t ws_size,
                              hipStream_t stream) {
    const float* initial = (const float*)d_in[0];
    const float* X       = (const float*)d_in[1];
    const float* alphas  = (const float*)d_in[2];
    const float* bias    = (const float*)d_in[3];
    float* out = (float*)d_out;

    crossnet_kernel<<<CN_BLOCKS, 256, 0, stream>>>(initial, X, alphas, bias, out);
}

// Round 4
// 306.860 us; speedup vs baseline: 1.0185x; 1.0185x over previous
//
#include <hip/hip_runtime.h>

// CrossNet fused kernel: out = initial * (X @ alphas) + X + bias
// B=16384 rows, D=2048 cols, fp32. One wave per row (R0 structure).
//
// R4: cache-policy experiment. R0-R3 proved duration (111us, 2.4 TB/s
// HBM) is invariant to occupancy (72/36/30%) and schedule -> not
// latency-bound. Counters show FETCH == exactly ONE array (131072 KiB)
// per dispatch: the 402 MB cyclic working set vs 256 MB L3 leaves a
// ~50% random-line subset resident, so HBM read misses are a random
// sprinkle of 128B lines (DRAM row-buffer hostile) -> ~2.4 TB/s cap.
// Fix attempt: segregate streams by cache policy. X loads stay
// default (L3-resident, 134 MB fits); initial loads and out stores
// are non-temporal (contiguous HBM streams, no L3 allocation). Only
// the hints differ from R0: clean A/B against 111us.

#define CN_D 2048
#define CN_ROWS 16384

typedef float vfloat4 __attribute__((ext_vector_type(4)));

__global__ __launch_bounds__(256) void crossnet_kernel(
    const float* __restrict__ initial,
    const float* __restrict__ X,
    const float* __restrict__ alphas,
    const float* __restrict__ bias,
    float* __restrict__ out)
{
    const int wave = threadIdx.x >> 6;          // 0..3
    const int lane = threadIdx.x & 63;
    const int row  = (blockIdx.x << 2) + wave;  // 4 rows per block

    const vfloat4* __restrict__ Xrow = (const vfloat4*)(X       + (size_t)row * CN_D);
    const vfloat4* __restrict__ Irow = (const vfloat4*)(initial + (size_t)row * CN_D);
    const vfloat4* __restrict__ A4   = (const vfloat4*)alphas;   // 8 KB, cached
    const vfloat4* __restrict__ B4   = (const vfloat4*)bias;     // 8 KB, cached
    vfloat4*       __restrict__ Orow = (vfloat4*)(out + (size_t)row * CN_D);

    // D/4 = 512 float4 per row; 64 lanes x 8 chunks, coalesced.
    // X: DEFAULT policy -> wants to live in L3 across bench iterations.
    float4 x[8];
    float acc = 0.0f;
#pragma unroll
    for (int k = 0; k < 8; ++k) {
        const int idx = (k << 6) + lane;
        x[k] = ((const float4*)Xrow)[idx];
        const vfloat4 a = A4[idx];
        acc += x[k].x * a.x + x[k].y * a.y + x[k].z * a.z + x[k].w * a.w;
    }

    // 64-lane butterfly reduction; xor leaves the sum in every lane.
#pragma unroll
    for (int off = 32; off > 0; off >>= 1)
        acc += __shfl_xor(acc, off, 64);

    // initial: NON-TEMPORAL loads -> no L3 allocation, contiguous HBM
    // read stream. out: NON-TEMPORAL stores -> contiguous HBM write
    // stream, no L3 pollution. L3 stays dedicated to X.
#pragma unroll
    for (int k = 0; k < 8; ++k) {
        const int idx = (k << 6) + lane;
        const vfloat4 i4 = __builtin_nontemporal_load(&Irow[idx]);
        const vfloat4 b4 = B4[idx];
        vfloat4 o;
        o.x = fmaf(i4.x, acc, x[k].x + b4.x);
        o.y = fmaf(i4.y, acc, x[k].y + b4.y);
        o.z = fmaf(i4.z, acc, x[k].z + b4.z);
        o.w = fmaf(i4.w, acc, x[k].w + b4.w);
        __builtin_nontemporal_store(o, &Orow[idx]);
    }
}

extern "C" void kernel_launch(void* const* d_in, const int* in_sizes, int n_in,
                              void* d_out, int out_size, void* d_ws, size_t ws_size,
                              hipStream_t stream) {
    const float* initial = (const float*)d_in[0];
    const float* X       = (const float*)d_in[1];
    const float* alphas  = (const float*)d_in[2];
    const float* bias    = (const float*)d_in[3];
    float* out = (float*)d_out;

    // 16384 rows / 4 rows per block = 4096 blocks of 256 threads.
    crossnet_kernel<<<CN_ROWS / 4, 256, 0, stream>>>(initial, X, alphas, bias, out);
}

// Round 5
// 297.258 us; speedup vs baseline: 1.0514x; 1.0323x over previous
//
#include <hip/hip_runtime.h>

// CrossNet fused kernel: out = initial * (X @ alphas) + X + bias
// B=16384 rows, D=2048 cols, fp32. One wave per row (R0 structure).
//
// R5: all-NT discriminator. R4 (NT on initial-loads + stores) gave
// 111->100.5us but FETCH stayed at exactly one array (131 GB-KiB),
// which is ambiguous: "initial all-miss + X all-hit" vs "NT loads
// ignored, both arrays ~50% randomly L3-resident". This round flips
// the one remaining stream (X loads) to NT -- single-variable A/B.
//   FETCH ~268MB -> load-NT honored; dur then measures the pure
//     contiguous-stream HBM rate with L3 out of the picture.
//   FETCH ~134MB -> MALL (memory-side L3) ignores load hints; the
//     read-side cache-policy lever does not exist on gfx950 and R4
//     was near the pattern-roofline.

#define CN_D 2048
#define CN_ROWS 16384

typedef float vfloat4 __attribute__((ext_vector_type(4)));

__global__ __launch_bounds__(256) void crossnet_kernel(
    const float* __restrict__ initial,
    const float* __restrict__ X,
    const float* __restrict__ alphas,
    const float* __restrict__ bias,
    float* __restrict__ out)
{
    const int wave = threadIdx.x >> 6;          // 0..3
    const int lane = threadIdx.x & 63;
    const int row  = (blockIdx.x << 2) + wave;  // 4 rows per block

    const vfloat4* __restrict__ Xrow = (const vfloat4*)(X       + (size_t)row * CN_D);
    const vfloat4* __restrict__ Irow = (const vfloat4*)(initial + (size_t)row * CN_D);
    const vfloat4* __restrict__ A4   = (const vfloat4*)alphas;   // 8 KB, cached
    const vfloat4* __restrict__ B4   = (const vfloat4*)bias;     // 8 KB, cached
    vfloat4*       __restrict__ Orow = (vfloat4*)(out + (size_t)row * CN_D);

    // D/4 = 512 float4 per row; 64 lanes x 8 chunks, coalesced.
    // X: NON-TEMPORAL this round (the single change vs R4).
    vfloat4 x[8];
    float acc = 0.0f;
#pragma unroll
    for (int k = 0; k < 8; ++k) {
        const int idx = (k << 6) + lane;
        x[k] = __builtin_nontemporal_load(&Xrow[idx]);
        const vfloat4 a = A4[idx];
        acc += x[k].x * a.x + x[k].y * a.y + x[k].z * a.z + x[k].w * a.w;
    }

    // 64-lane butterfly reduction; xor leaves the sum in every lane.
#pragma unroll
    for (int off = 32; off > 0; off >>= 1)
        acc += __shfl_xor(acc, off, 64);

    // initial: NT loads; out: NT stores (both as in R4).
#pragma unroll
    for (int k = 0; k < 8; ++k) {
        const int idx = (k << 6) + lane;
        const vfloat4 i4 = __builtin_nontemporal_load(&Irow[idx]);
        const vfloat4 b4 = B4[idx];
        vfloat4 o;
        o.x = fmaf(i4.x, acc, x[k].x + b4.x);
        o.y = fmaf(i4.y, acc, x[k].y + b4.y);
        o.z = fmaf(i4.z, acc, x[k].z + b4.z);
        o.w = fmaf(i4.w, acc, x[k].w + b4.w);
        __builtin_nontemporal_store(o, &Orow[idx]);
    }
}

extern "C" void kernel_launch(void* const* d_in, const int* in_sizes, int n_in,
                              void* d_out, int out_size, void* d_ws, size_t ws_size,
                              hipStream_t stream) {
    const float* initial = (const float*)d_in[0];
    const float* X       = (const float*)d_in[1];
    const float* alphas  = (const float*)d_in[2];
    const float* bias    = (const float*)d_in[3];
    float* out = (float*)d_out;

    // 16384 rows / 4 rows per block = 4096 blocks of 256 threads.
    crossnet_kernel<<<CN_ROWS / 4, 256, 0, stream>>>(initial, X, alphas, bias, out);
}

// Round 6
// 295.266 us; speedup vs baseline: 1.0585x; 1.0067x over previous
//
#include <hip/hip_runtime.h>

// CrossNet fused kernel: out = initial * (X @ alphas) + X + bias
// B=16384 rows, D=2048 cols, fp32. One wave per row.
//
// R6: all-NT (R5, kept: ~78us, 5.1 TB/s demand) + single merged HBM
// wait per row (R2's dataflow-fence structure, re-run in the new
// regime). R2 was a no-op under L3-thrash because DRAM scatter capped
// everything; with NT streams the per-wave timeline (900cy X-wait +
// reduce + 900cy I-wait) is the marginal term: 12.3 B/cyc/CU demanded
// vs 10.25 needed. Issuing all 16 row loads before the reduce halves
// wave residency -> doubles issue-rate slack. Single variable vs R5.

#define CN_D 2048
#define CN_ROWS 16384

typedef float vfloat4 __attribute__((ext_vector_type(4)));

__global__ __launch_bounds__(256) void crossnet_kernel(
    const float* __restrict__ initial,
    const float* __restrict__ X,
    const float* __restrict__ alphas,
    const float* __restrict__ bias,
    float* __restrict__ out)
{
    const int wave = threadIdx.x >> 6;          // 0..3
    const int lane = threadIdx.x & 63;
    const int row  = (blockIdx.x << 2) + wave;  // 4 rows per block

    const vfloat4* __restrict__ Xrow = (const vfloat4*)(X       + (size_t)row * CN_D);
    const vfloat4* __restrict__ Irow = (const vfloat4*)(initial + (size_t)row * CN_D);
    const vfloat4* __restrict__ A4   = (const vfloat4*)alphas;   // 8 KB, cached
    const vfloat4* __restrict__ B4   = (const vfloat4*)bias;     // 8 KB, cached
    vfloat4*       __restrict__ Orow = (vfloat4*)(out + (size_t)row * CN_D);

    // D/4 = 512 float4 per row; 64 lanes x 8 chunks, coalesced.
    // Issue BOTH row streams back-to-back: 16 NT loads in flight.
    vfloat4 x[8];
    vfloat4 fi[8];
#pragma unroll
    for (int k = 0; k < 8; ++k) x[k]  = __builtin_nontemporal_load(&Xrow[(k << 6) + lane]);
#pragma unroll
    for (int k = 0; k < 8; ++k) fi[k] = __builtin_nontemporal_load(&Irow[(k << 6) + lane]);

    // Dot against alphas (cached) while the HBM loads drain.
    float acc = 0.0f;
#pragma unroll
    for (int k = 0; k < 8; ++k) {
        const vfloat4 a = A4[(k << 6) + lane];
        acc = fmaf(x[k].x, a.x, acc);
        acc = fmaf(x[k].y, a.y, acc);
        acc = fmaf(x[k].z, a.z, acc);
        acc = fmaf(x[k].w, a.w, acc);
    }

    // Fold bias pre-reduce: post-reduce path is pure FMA + store.
#pragma unroll
    for (int k = 0; k < 8; ++k)
        x[k] += B4[(k << 6) + lane];

    // Dataflow fence: the reduce input depends on every fi/x value, so
    // the shuffle chain cannot start before the initial-loads complete
    // and fi/x stay live in VGPRs (no second load phase after reduce).
#pragma unroll
    for (int k = 0; k < 8; ++k)
        asm("" : "+v"(acc) : "v"(fi[k]), "v"(x[k]));

    // 64-lane butterfly; xor leaves the full sum in every lane.
#pragma unroll
    for (int off = 32; off > 0; off >>= 1)
        acc += __shfl_xor(acc, off, 64);

    // Epilogue: zero loads on the critical path; NT stores.
#pragma unroll
    for (int k = 0; k < 8; ++k) {
        vfloat4 o;
        o.x = fmaf(fi[k].x, acc, x[k].x);
        o.y = fmaf(fi[k].y, acc, x[k].y);
        o.z = fmaf(fi[k].z, acc, x[k].z);
        o.w = fmaf(fi[k].w, acc, x[k].w);
        __builtin_nontemporal_store(o, &Orow[(k << 6) + lane]);
    }
}

extern "C" void kernel_launch(void* const* d_in, const int* in_sizes, int n_in,
                              void* d_out, int out_size, void* d_ws, size_t ws_size,
                              hipStream_t stream) {
    const float* initial = (const float*)d_in[0];
    const float* X       = (const float*)d_in[1];
    const float* alphas  = (const float*)d_in[2];
    const float* bias    = (const float*)d_in[3];
    float* out = (float*)d_out;

    // 16384 rows / 4 rows per block = 4096 blocks of 256 threads.
    crossnet_kernel<<<CN_ROWS / 4, 256, 0, stream>>>(initial, X, alphas, bias, out);
}